// Round 4
// baseline (166.365 us; speedup 1.0000x reference)
//
#include <hip/hip_runtime.h>
#include <math.h>

#define W 512
#define H 512
#define IMG (W * H)
#define SB 84          // LDS row stride (floats)
#define LROWS 76       // staged rows: tile rows [-6, 70)

// ---------------- compile-time operator tables ----------------
// 1D composed second-difference D = diff(diff(.)) from the reference.
// Row i, coefficient of u_j. Valid for the low-boundary region (i,j << N);
// the high end is handled by mirror symmetry at the call sites.
__host__ __device__ constexpr double dcoefd(int i, int j) {
    if (i == 0) return j == 0 ? 0.5 : j == 1 ? -1.0 : j == 2 ? 0.5 : 0.0;
    if (i == 1) return j == 0 ? 0.5 : j == 1 ? -0.75 : j == 3 ? 0.25 : 0.0;
    return j == i - 2 ? 0.25 : j == i ? -0.5 : j == i + 2 ? 0.25 : 0.0;
}

// Boundary rows of D, D^2, D^3 for output index 0..5 (support <= 11 < 16).
struct BTabT {
    float w1[6][16], w2[6][16], w3[6][16];
    constexpr BTabT() : w1{}, w2{}, w3{} {
        for (int i = 0; i < 6; ++i) {
            double r1[20] = {}, r2[20] = {};
            for (int j = 0; j < 20; ++j) r1[j] = dcoefd(i, j);
            for (int j = 0; j < 16; ++j) {
                double s = 0;
                for (int k = 0; k < 18; ++k) s += r1[k] * dcoefd(k, j);
                r2[j] = s;
            }
            for (int j = 0; j < 16; ++j) {
                double s = 0;
                for (int k = 0; k < 16; ++k) s += r2[k] * dcoefd(k, j);
                w3[i][j] = (float)s;
            }
            for (int j = 0; j < 16; ++j) {
                w1[i][j] = (float)r1[j];
                w2[i][j] = (float)r2[j];
            }
        }
    }
};
__device__ constexpr BTabT BT{};
__device__ constexpr float cP1[3] = {0.25f, -0.5f, 0.25f};
__device__ constexpr float cP2[5] = {0.0625f, -0.25f, 0.375f, -0.25f, 0.0625f};
__device__ constexpr float cP3[7] = {1.f/64, -6.f/64, 15.f/64, -20.f/64, 15.f/64, -6.f/64, 1.f/64};

// Pure (interior) tap of D^a at even offset 2d.
__host__ __device__ constexpr float PT(int a, int d) {
    if (a == 0) return d == 0 ? 1.f : 0.f;
    if (a == 1) return (d == -1 || d == 1) ? 0.25f : d == 0 ? -0.5f : 0.f;
    if (a == 2) return (d == -2 || d == 2) ? 0.0625f
                      : (d == -1 || d == 1) ? -0.25f : d == 0 ? 0.375f : 0.f;
    return (d == -3 || d == 3) ? (1.f/64) : (d == -2 || d == 2) ? (-6.f/64)
         : (d == -1 || d == 1) ? (15.f/64) : d == 0 ? (-20.f/64) : 0.f;
}

// Coefficient of X^a Y^b in 10B + 45B^2 + 120B^3, B = X + Y.
__host__ __device__ constexpr float Ccoef(int a, int b) {
    const int n = a + b;
    const float c[4] = {0.f, 10.f, 45.f, 120.f};
    int bin = 1;
    for (int t = 0; t < a; ++t) bin = bin * (n - t) / (t + 1);
    return c[n] * (float)bin;
}

__device__ __forceinline__ float4 ld4(const float* p) {
    return *reinterpret_cast<const float4*>(p);
}

// One block per 64x64 tile. Thread t: quad-col x0 = (t&15)*4, row group
// y0 = ((t>>4)>>1)*8 + ((t>>4)&1); owns 4 output quads at rows y0+2k.
__global__ __launch_bounds__(256) void fused_poly(
        const float* __restrict__ u, float* __restrict__ outp,
        const float* __restrict__ alpha, const float* __restrict__ beta,
        const float* __restrict__ axp, const float* __restrict__ ayp,
        const float* __restrict__ es) {
    __shared__ float lds0[LROWS * SB];

    // XCD-chunked bijective swizzle (grid = 4096 = 8*512).
    unsigned bid = blockIdx.x;
    unsigned swz = (bid & 7u) * (gridDim.x >> 3) + (bid >> 3);
    unsigned img  = swz >> 6;
    unsigned tile = swz & 63u;
    const int gx0 = (int)(tile & 7u) << 6;
    const int gy0 = (int)(tile >> 3) << 6;
    const float* __restrict__ p = u + (size_t)img * IMG;
    float* __restrict__ qout = outp + (size_t)img * IMG;

    const float sx = 0.01f * alpha[0] * axp[0];
    const float sy = 0.01f * beta[0]  * ayp[0];
    const float sx2 = sx * sx, sx3 = sx2 * sx;
    const float sy2 = sy * sy, sy3 = sy2 * sy;
    const float am = 1.0f / (1.0f + expf(-es[0]));

    const int tid = threadIdx.x;

    // ---- stage u tile + halo: rows [-6,70) x cols [-8,72), clamped ----
    for (int t = tid; t < LROWS * 20; t += 256) {
        int rr = t / 20, cc = t % 20;
        int gy = gy0 + rr - 6, gx = gx0 + (cc << 2) - 8;
        if ((unsigned)gy < (unsigned)H && (unsigned)gx < (unsigned)W)
            *reinterpret_cast<float4*>(&lds0[rr * SB + (cc << 2)]) =
                ld4(p + gy * W + gx);
    }
    __syncthreads();

    const int qc = tid & 15, g = tid >> 4;
    const int y0 = ((g >> 1) << 3) + (g & 1);
    const int x0 = qc << 2;

    // ---- combined interior taps T[dy+3][dx+3] (even lattice) ----
    float T[7][7];
    {
        const float sxp[4] = {1.f, sx, sx2, sx3};
        const float syp[4] = {1.f, sy, sy2, sy3};
        #pragma unroll
        for (int qy = -3; qy <= 3; ++qy) {
            #pragma unroll
            for (int px_ = -3; px_ <= 3; ++px_) {
                float s = 0.f;
                #pragma unroll
                for (int a = 0; a <= 3; ++a) {
                    #pragma unroll
                    for (int b = 0; b <= 3; ++b) {
                        if (a + b > 3 || (a == 0 && b == 0)) continue;
                        const int ap = px_ < 0 ? -px_ : px_;
                        const int aq = qy < 0 ? -qy : qy;
                        if (ap > a || aq > b) continue;
                        s += Ccoef(a, b) * PT(a, px_) * PT(b, qy) * sxp[a] * syp[b];
                    }
                }
                T[qy + 3][px_ + 3] = s;
            }
        }
    }

    const bool yb = (gy0 == 0 && y0 < 2) || (gy0 == H - 64 && y0 >= 56);
    const bool xb = (gx0 == 0 && x0 < 8) || (gx0 == W - 64 && x0 >= 56);

    constexpr int ROWS[10] = {-6,-4,-2,0,2,4,6,8,10,12};
    constexpr int AMX[10]  = {0,1,2,3,3,3,3,2,1,0};

    float acc[4][4] = {{0.f,0.f,0.f,0.f},{0.f,0.f,0.f,0.f},
                       {0.f,0.f,0.f,0.f},{0.f,0.f,0.f,0.f}};

    if (!yb && !xb) {
        // ---------------- hot path: pure 25-tap ----------------
        #pragma unroll
        for (int ri = 0; ri < 10; ++ri) {
            const int rr = ROWS[ri], amx = AMX[ri];
            const float* lrow = &lds0[(y0 + rr + 6) * SB + x0 + 8];
            float rb[20];
            if (amx == 3) {
                #pragma unroll
                for (int c5 = 0; c5 < 5; ++c5)
                    *reinterpret_cast<float4*>(&rb[4 * c5]) = ld4(lrow - 8 + 4 * c5);
            } else if (amx >= 1) {
                #pragma unroll
                for (int c5 = 1; c5 < 4; ++c5)
                    *reinterpret_cast<float4*>(&rb[4 * c5]) = ld4(lrow - 8 + 4 * c5);
            } else {
                *reinterpret_cast<float4*>(&rb[8]) = ld4(lrow);
            }
            #pragma unroll
            for (int k = 0; k < 4; ++k) {
                const int dq = rr / 2 - k;
                const int adq = dq < 0 ? -dq : dq;
                if (adq > 3) continue;
                const int pm = 3 - adq;
                #pragma unroll
                for (int pp = -pm; pp <= pm; ++pp) {
                    const float t = T[dq + 3][pp + 3];
                    #pragma unroll
                    for (int j = 0; j < 4; ++j)
                        acc[k][j] = fmaf(t, rb[8 + j + 2 * pp], acc[k][j]);
                }
            }
        }
    } else if (!yb) {
        // ---------- x-boundary quad, interior-y rows ----------
        #pragma unroll
        for (int ri = 0; ri < 10; ++ri) {
            const int rr = ROWS[ri], amx = AMX[ri];
            const int lr = y0 + rr + 6;
            const float* lrow = &lds0[lr * SB + x0 + 8];
            float rb[20];
            if (amx == 3) {
                #pragma unroll
                for (int c5 = 0; c5 < 5; ++c5)
                    *reinterpret_cast<float4*>(&rb[4 * c5]) = ld4(lrow - 8 + 4 * c5);
            } else if (amx >= 1) {
                #pragma unroll
                for (int c5 = 1; c5 < 4; ++c5)
                    *reinterpret_cast<float4*>(&rb[4 * c5]) = ld4(lrow - 8 + 4 * c5);
            } else {
                *reinterpret_cast<float4*>(&rb[8]) = ld4(lrow);
            }
            float M0v[4], M1v[4], M2v[4], M3v[4];
            #pragma unroll
            for (int j = 0; j < 4; ++j) {
                const int gx = gx0 + x0 + j;
                const float u0 = rb[8 + j];
                float xc1 = 0.f, xc2 = 0.f, xc3 = 0.f;
                if (amx >= 1) {
                    if (gx >= 6 && gx <= W - 7) {
                        xc1 = sx * (0.25f * (rb[6+j] + rb[10+j]) - 0.5f * u0);
                        if (amx >= 2)
                            xc2 = sx2 * (0.0625f * (rb[4+j] + rb[12+j])
                                  - 0.25f * (rb[6+j] + rb[10+j]) + 0.375f * u0);
                        if (amx >= 3)
                            xc3 = sx3 * ((1.f/64) * (rb[2+j] + rb[14+j])
                                  - (6.f/64) * (rb[4+j] + rb[12+j])
                                  + (15.f/64) * (rb[6+j] + rb[10+j]) - (20.f/64) * u0);
                    } else {
                        const bool lowx = gx < 6;
                        const int xi = lowx ? gx : (W - 1) - gx;
                        float s1 = 0.f, s2 = 0.f, s3 = 0.f;
                        for (int jj = 0; jj < 12; ++jj) {
                            const int col = lowx ? jj : (W - 1) - jj;
                            const float uv = lds0[lr * SB + (col - gx0 + 8)];
                            s1 = fmaf(BT.w1[xi][jj], uv, s1);
                            s2 = fmaf(BT.w2[xi][jj], uv, s2);
                            s3 = fmaf(BT.w3[xi][jj], uv, s3);
                        }
                        xc1 = sx * s1; xc2 = sx2 * s2; xc3 = sx3 * s3;
                    }
                }
                M0v[j] = 10.f*xc1 + 45.f*xc2 + 120.f*xc3;
                M1v[j] = 10.f*u0 + 90.f*xc1 + 360.f*xc2;
                M2v[j] = 45.f*u0 + 360.f*xc1;
                M3v[j] = 120.f*u0;
            }
            #pragma unroll
            for (int k = 0; k < 4; ++k) {
                const int dq = rr / 2 - k;
                const int adq = dq < 0 ? -dq : dq;
                if (adq > 3) continue;
                #pragma unroll
                for (int j = 0; j < 4; ++j) {
                    float c = 0.f;
                    if (dq == 0) c += M0v[j];
                    if (adq <= 1) c += PT(1, dq) * sy * M1v[j];
                    if (adq <= 2) c += PT(2, dq) * sy2 * M2v[j];
                    c += PT(3, dq) * sy3 * M3v[j];
                    acc[k][j] += c;
                }
            }
        }
    } else {
        // ---------- y-boundary thread (handles corner px too) ----------
        const bool lowy = (gy0 == 0);
        #pragma unroll 1
        for (int ri = 0; ri < 14; ++ri) {
            const int r = lowy ? ri : (H - 14) + ri;
            const int lr = r - gy0 + 6;
            const float* lrow = &lds0[lr * SB + x0 + 8];
            float rb[20];
            #pragma unroll
            for (int c5 = 0; c5 < 5; ++c5)
                *reinterpret_cast<float4*>(&rb[4 * c5]) = ld4(lrow - 8 + 4 * c5);
            float M0v[4], M1v[4], M2v[4], M3v[4];
            #pragma unroll
            for (int j = 0; j < 4; ++j) {
                const int gx = gx0 + x0 + j;
                const float u0 = rb[8 + j];
                float xc1, xc2, xc3;
                if (gx >= 6 && gx <= W - 7) {
                    xc1 = sx * (0.25f * (rb[6+j] + rb[10+j]) - 0.5f * u0);
                    xc2 = sx2 * (0.0625f * (rb[4+j] + rb[12+j])
                          - 0.25f * (rb[6+j] + rb[10+j]) + 0.375f * u0);
                    xc3 = sx3 * ((1.f/64) * (rb[2+j] + rb[14+j])
                          - (6.f/64) * (rb[4+j] + rb[12+j])
                          + (15.f/64) * (rb[6+j] + rb[10+j]) - (20.f/64) * u0);
                } else {
                    const bool lowx = gx < 6;
                    const int xi = lowx ? gx : (W - 1) - gx;
                    float s1 = 0.f, s2 = 0.f, s3 = 0.f;
                    for (int jj = 0; jj < 12; ++jj) {
                        const int col = lowx ? jj : (W - 1) - jj;
                        const float uv = lds0[lr * SB + (col - gx0 + 8)];
                        s1 = fmaf(BT.w1[xi][jj], uv, s1);
                        s2 = fmaf(BT.w2[xi][jj], uv, s2);
                        s3 = fmaf(BT.w3[xi][jj], uv, s3);
                    }
                    xc1 = sx * s1; xc2 = sx2 * s2; xc3 = sx3 * s3;
                }
                M0v[j] = 10.f*xc1 + 45.f*xc2 + 120.f*xc3;
                M1v[j] = 10.f*u0 + 90.f*xc1 + 360.f*xc2;
                M2v[j] = 45.f*u0 + 360.f*xc1;
                M3v[j] = 120.f*u0;
            }
            #pragma unroll
            for (int k = 0; k < 4; ++k) {
                const int Yo = gy0 + y0 + 2 * k;
                float wy0, wy1, wy2, wy3;
                if (Yo >= 6 && Yo <= H - 7) {
                    const int d = r - Yo;
                    const int h = d / 2;
                    const bool ev = (d & 1) == 0;
                    wy0 = (d == 0) ? 1.f : 0.f;
                    wy1 = (ev && h >= -1 && h <= 1) ? cP1[h + 1] : 0.f;
                    wy2 = (ev && h >= -2 && h <= 2) ? cP2[h + 2] : 0.f;
                    wy3 = (ev && h >= -3 && h <= 3) ? cP3[h + 3] : 0.f;
                } else {
                    const int yi = lowy ? Yo : (H - 1) - Yo;
                    const int jr = lowy ? r : (H - 1) - r;
                    wy0 = (r == Yo) ? 1.f : 0.f;
                    wy1 = BT.w1[yi][jr];
                    wy2 = BT.w2[yi][jr];
                    wy3 = BT.w3[yi][jr];
                }
                #pragma unroll
                for (int j = 0; j < 4; ++j)
                    acc[k][j] += wy0 * M0v[j] + sy * wy1 * M1v[j]
                               + sy2 * wy2 * M2v[j] + sy3 * wy3 * M3v[j];
            }
        }
    }

    // ---- out = u + am * (P u) ----
    #pragma unroll
    for (int k = 0; k < 4; ++k) {
        const float4 u4 = ld4(&lds0[(y0 + 2 * k + 6) * SB + x0 + 8]);
        float4 o;
        o.x = u4.x + am * acc[k][0];
        o.y = u4.y + am * acc[k][1];
        o.z = u4.z + am * acc[k][2];
        o.w = u4.w + am * acc[k][3];
        *reinterpret_cast<float4*>(qout + (gy0 + y0 + 2 * k) * W + gx0 + x0) = o;
    }
}

extern "C" void kernel_launch(void* const* d_in, const int* in_sizes, int n_in,
                              void* d_out, int out_size, void* d_ws, size_t ws_size,
                              hipStream_t stream) {
    const float* u     = (const float*)d_in[0];
    const float* alpha = (const float*)d_in[1];
    const float* beta  = (const float*)d_in[2];
    const float* ax    = (const float*)d_in[3];
    const float* ay    = (const float*)d_in[4];
    const float* es    = (const float*)d_in[5];
    float* out = (float*)d_out;

    int nimg = in_sizes[0] / IMG;            // 64 images
    dim3 block(256);
    dim3 grid((unsigned)(nimg * 64));        // 8x8 tiles per image
    fused_poly<<<grid, block, 0, stream>>>(u, out, alpha, beta, ax, ay, es);
}

// Round 5
// 73.049 us; speedup vs baseline: 2.2775x; 2.2775x over previous
//
#include <hip/hip_runtime.h>
#include <math.h>

#define W 512
#define H 512
#define IMG (W * H)

// ---------------- compile-time operator tables ----------------
// 1D composed second-difference D = diff(diff(.)) from the reference.
// Row i, coefficient of u_j (low-boundary form; high end by mirror symmetry).
__host__ __device__ constexpr double dcoefd(int i, int j) {
    if (i == 0) return j == 0 ? 0.5 : j == 1 ? -1.0 : j == 2 ? 0.5 : 0.0;
    if (i == 1) return j == 0 ? 0.5 : j == 1 ? -0.75 : j == 3 ? 0.25 : 0.0;
    return j == i - 2 ? 0.25 : j == i ? -0.5 : j == i + 2 ? 0.25 : 0.0;
}

// Boundary rows of D, D^2, D^3 for output index 0..5.
struct BTabT {
    float w1[6][16], w2[6][16], w3[6][16];
    constexpr BTabT() : w1{}, w2{}, w3{} {
        for (int i = 0; i < 6; ++i) {
            double r1[20] = {}, r2[20] = {};
            for (int j = 0; j < 20; ++j) r1[j] = dcoefd(i, j);
            for (int j = 0; j < 16; ++j) {
                double s = 0;
                for (int k = 0; k < 18; ++k) s += r1[k] * dcoefd(k, j);
                r2[j] = s;
            }
            for (int j = 0; j < 16; ++j) {
                double s = 0;
                for (int k = 0; k < 16; ++k) s += r2[k] * dcoefd(k, j);
                w3[i][j] = (float)s;
            }
            for (int j = 0; j < 16; ++j) { w1[i][j] = (float)r1[j]; w2[i][j] = (float)r2[j]; }
        }
    }
};
constexpr BTabT BT{};

// Pure (interior) tap of D^a at even offset 2d.
__host__ __device__ constexpr float PT(int a, int d) {
    if (a == 0) return d == 0 ? 1.f : 0.f;
    if (a == 1) return (d == -1 || d == 1) ? 0.25f : d == 0 ? -0.5f : 0.f;
    if (a == 2) return (d == -2 || d == 2) ? 0.0625f
                      : (d == -1 || d == 1) ? -0.25f : d == 0 ? 0.375f : 0.f;
    return (d == -3 || d == 3) ? (1.f/64) : (d == -2 || d == 2) ? (-6.f/64)
         : (d == -1 || d == 1) ? (15.f/64) : d == 0 ? (-20.f/64) : 0.f;
}

// 1D weight of D^b (boundary-aware) at output row Yo, input row r.
__host__ __device__ constexpr float wcoefB(int b, int Yo, int r) {
    if (Yo >= 6 && Yo <= H - 7) {
        const int d = r - Yo;
        if ((d & 1) != 0) return 0.f;
        const int h = d / 2;
        const int ah = h < 0 ? -h : h;
        if (ah > b) return 0.f;
        return PT(b, h);
    }
    const int yi = Yo < 6 ? Yo : (H - 1) - Yo;
    const int jr = Yo < 6 ? r : (H - 1) - r;
    if (jr < 0 || jr > 15) return 0.f;
    return b == 1 ? BT.w1[yi][jr] : b == 2 ? BT.w2[yi][jr] : BT.w3[yi][jr];
}

// Ghost-cell coefficients: u_{-k} = sum_j g[k][j]*u_j makes the PURE stencils
// of D, D^2, D^3 reproduce the boundary-aware operator exactly (derived from
// matching pure rows 0,1 of each power; rows >=2 match automatically).
struct GhostT {
    float g[7][8];
    constexpr GhostT() : g{} {
        double v0[8] = {}, v1[8] = {}, v2[8] = {}, w0[8] = {}, w1r[8] = {}, w2r[8] = {};
        for (int j = 0; j < 8; ++j) { v0[j] = dcoefd(0, j); v1[j] = dcoefd(1, j); v2[j] = dcoefd(2, j); }
        for (int j = 0; j < 8; ++j) {
            double s0 = 0, s1 = 0, s2 = 0;
            for (int k = 0; k < 10; ++k) {
                s0 += dcoefd(0, k) * dcoefd(k, j);
                s1 += dcoefd(1, k) * dcoefd(k, j);
                s2 += dcoefd(2, k) * dcoefd(k, j);
            }
            w0[j] = s0; w1r[j] = s1; w2r[j] = s2;
        }
        double um1[8] = {}, um2[8] = {}, um3[8] = {}, um4[8] = {}, um5[8] = {}, um6[8] = {};
        double vm1[8] = {}, vm2[8] = {}, vm3[8] = {}, vm4[8] = {}, wm1[8] = {}, wm2[8] = {};
        for (int j = 0; j < 8; ++j) {
            um1[j] = 2.0 * (j == 0) - (j == 1);
            um2[j] = 4.0 * (j == 0) - 4.0 * (j == 1) + (j == 2);
            vm1[j] = 2 * v0[j] - v1[j];
            vm2[j] = 4 * v0[j] - 4 * v1[j] + v2[j];
            wm1[j] = 2 * w0[j] - w1r[j];
            wm2[j] = 4 * w0[j] - 4 * w1r[j] + w2r[j];
        }
        for (int j = 0; j < 8; ++j) {
            um3[j] = 4 * vm1[j] + 2 * um1[j] - (j == 1);
            um4[j] = 4 * vm2[j] + 2 * um2[j] - (j == 0);
            vm3[j] = 4 * wm1[j] + 2 * vm1[j] - v1[j];
            vm4[j] = 4 * wm2[j] + 2 * vm2[j] - v0[j];
        }
        for (int j = 0; j < 8; ++j) {
            um5[j] = 4 * vm3[j] + 2 * um3[j] - um1[j];
            um6[j] = 4 * vm4[j] + 2 * um4[j] - um2[j];
        }
        for (int j = 0; j < 8; ++j) {
            g[1][j] = (float)um1[j]; g[2][j] = (float)um2[j]; g[3][j] = (float)um3[j];
            g[4][j] = (float)um4[j]; g[5][j] = (float)um5[j]; g[6][j] = (float)um6[j];
        }
    }
};
constexpr GhostT GH{};

// y-weight table for boundary bands: [ly(0=low,1=high)][g][ri(14)][k(4)][b(4)]
struct WYTabT {
    float w[2][2][14][4][4];
    constexpr WYTabT() : w{} {
        for (int ly = 0; ly < 2; ++ly)
        for (int gg = 0; gg < 2; ++gg)
        for (int ri = 0; ri < 14; ++ri)
        for (int k = 0; k < 4; ++k) {
            const int r  = ly == 0 ? ri : (H - 14) + ri;
            const int Yo = (ly == 0 ? 0 : H - 8) + gg + 2 * k;
            w[ly][gg][ri][k][0] = (r == Yo) ? 1.f : 0.f;
            w[ly][gg][ri][k][1] = wcoefB(1, Yo, r);
            w[ly][gg][ri][k][2] = wcoefB(2, Yo, r);
            w[ly][gg][ri][k][3] = wcoefB(3, Yo, r);
        }
    }
};
__device__ constexpr WYTabT WYT{};

__device__ __forceinline__ float4 ld4(const float* p) {
    return *reinterpret_cast<const float4*>(p);
}
__device__ __forceinline__ float rfl(float x) {
    return __int_as_float(__builtin_amdgcn_readfirstlane(__float_as_int(x)));
}

struct Uni {
    float k1, k2, k3, m1, m2, n1;                              // x-side M consts
    float wy1a, wy1b, wy2a, wy2b, wy2c, wy3a, wy3b, wy3c, wy3d; // interior y-weights
    float sy1, sy2, sy3;                                        // y powers
    float am;
};

// Patch ghost columns into rb for the 4 edge lanes; after this the pure
// formulas are exact for every j. rb[i] = u at col gx0-8+i.
__device__ __forceinline__ void patch_rb(float rb[20], int c) {
    if (c == 0) {                       // cols -6..-1 -> rb[2..7]
        #pragma unroll
        for (int k = 1; k <= 6; ++k) {
            float s = 0.f;
            #pragma unroll
            for (int j = 0; j < 8; ++j) {
                const float w = GH.g[k][j];
                if (w != 0.f) s = fmaf(w, rb[8 + j], s);
            }
            rb[8 - k] = s;
        }
    } else if (c == 1) {                // cols -2..-1 -> rb[2..3]
        #pragma unroll
        for (int k = 1; k <= 2; ++k) {
            float s = 0.f;
            #pragma unroll
            for (int j = 0; j < 8; ++j) {
                const float w = GH.g[k][j];
                if (w != 0.f) s = fmaf(w, rb[4 + j], s);
            }
            rb[4 - k] = s;
        }
    } else if (c == 126) {              // cols 512..513 -> rb[16..17]
        #pragma unroll
        for (int k = 1; k <= 2; ++k) {
            float s = 0.f;
            #pragma unroll
            for (int j = 0; j < 8; ++j) {
                const float w = GH.g[k][j];
                if (w != 0.f) s = fmaf(w, rb[15 - j], s);
            }
            rb[15 + k] = s;
        }
    } else if (c == 127) {              // cols 512..517 -> rb[12..17]
        #pragma unroll
        for (int k = 1; k <= 6; ++k) {
            float s = 0.f;
            #pragma unroll
            for (int j = 0; j < 8; ++j) {
                const float w = GH.g[k][j];
                if (w != 0.f) s = fmaf(w, rb[11 - j], s);
            }
            rb[11 + k] = s;
        }
    }
}

// Per-row composites: X_a = D_x^a u (unscaled), then
// M0 = 10sx X1 + 45sx^2 X2 + 120sx^3 X3 ; M1 = 10u + 90sx X1 + 360sx^2 X2
// M2 = 45u + 360sx X1 ; M3 = 120u
__device__ __forceinline__ void rowM(const Uni& U, float rb[20], int c,
                                     float M0[4], float M1[4], float M2[4], float M3[4]) {
    if ((unsigned)(c - 2) > 123u) patch_rb(rb, c);
    #pragma unroll
    for (int j = 0; j < 4; ++j) {
        const float u0 = rb[8 + j];
        const float p1 = rb[6 + j] + rb[10 + j];
        const float p2 = rb[4 + j] + rb[12 + j];
        const float p3 = rb[2 + j] + rb[14 + j];
        const float X1 = fmaf(0.25f, p1, -0.5f * u0);
        const float X2 = fmaf(0.0625f, p2, fmaf(-0.25f, p1, 0.375f * u0));
        const float X3 = fmaf(1.f/64, p3, fmaf(-6.f/64, p2, fmaf(15.f/64, p1, (-20.f/64) * u0)));
        M0[j] = fmaf(U.k1, X1, fmaf(U.k2, X2, U.k3 * X3));
        M1[j] = fmaf(U.m1, X1, fmaf(U.m2, X2, 10.f * u0));
        M2[j] = fmaf(U.n1, X1, 45.f * u0);
        M3[j] = 120.f * u0;
    }
}

__global__ __launch_bounds__(256) void fused_band(
        const float* __restrict__ uin, float* __restrict__ outp,
        const float* __restrict__ alpha, const float* __restrict__ beta,
        const float* __restrict__ axp, const float* __restrict__ ayp,
        const float* __restrict__ es) {
    // XCD-chunked bijective swizzle (m204 form)
    const unsigned bid = blockIdx.x, nwg = gridDim.x;
    const unsigned xcd = bid & 7u, ib = bid >> 3;
    const unsigned qq = nwg >> 3, rr = nwg & 7u;
    const unsigned swz = (xcd < rr ? xcd * (qq + 1u) : rr * (qq + 1u) + (xcd - rr) * qq) + ib;

    const unsigned img  = swz >> 6;     // 64 bands of 8 rows per image
    const unsigned band = swz & 63u;
    const int y0 = (int)band << 3;
    const float* __restrict__ p = uin + (size_t)img * IMG;
    float* __restrict__ q = outp + (size_t)img * IMG;

    const float sx = 0.01f * alpha[0] * axp[0];
    const float sy = 0.01f * beta[0]  * ayp[0];
    Uni U;
    U.k1 = rfl(10.f * sx);  U.k2 = rfl(45.f * sx * sx);  U.k3 = rfl(120.f * sx * sx * sx);
    U.m1 = rfl(90.f * sx);  U.m2 = rfl(360.f * sx * sx); U.n1 = rfl(360.f * sx);
    const float sy2 = sy * sy, sy3 = sy2 * sy;
    U.sy1 = rfl(sy); U.sy2 = rfl(sy2); U.sy3 = rfl(sy3);
    U.wy1a = rfl(0.25f * sy);    U.wy1b = rfl(-0.5f * sy);
    U.wy2a = rfl(0.0625f * sy2); U.wy2b = rfl(-0.25f * sy2); U.wy2c = rfl(0.375f * sy2);
    U.wy3a = rfl((1.f/64) * sy3);  U.wy3b = rfl((-6.f/64) * sy3);
    U.wy3c = rfl((15.f/64) * sy3); U.wy3d = rfl((-20.f/64) * sy3);
    U.am = rfl(1.f / (1.f + expf(-es[0])));

    const int tid = threadIdx.x;
    const int g = tid >> 7;                      // row-parity group (uniform/wave)
    const int c = ((tid & 127) + 2) & 127;       // rotate: edges cluster in odd waves
    const int gx0 = c << 2;

    int colm[5];
    #pragma unroll
    for (int m = 0; m < 5; ++m) {
        int col = gx0 - 8 + 4 * m;
        colm[m] = col < 0 ? 0 : (col > W - 4 ? W - 4 : col);
    }

    float acc[4][4] = {};

    if (band >= 1 && band <= 62) {
        // ---------------- interior band (y pure) ----------------
        const int yb0 = y0 + g;                  // outputs at yb0 + 2k
        #pragma unroll
        for (int ri = 0; ri < 10; ++ri) {
            const int r = yb0 - 6 + 2 * ri;
            float rb[20];
            #pragma unroll
            for (int m = 0; m < 5; ++m)
                *reinterpret_cast<float4*>(&rb[4 * m]) = ld4(p + (size_t)r * W + colm[m]);
            float M0[4], M1[4], M2[4], M3[4];
            rowM(U, rb, c, M0, M1, M2, M3);
            #pragma unroll
            for (int k = 0; k < 4; ++k) {
                const int dq = ri - 3 - k;
                const int ad = dq < 0 ? -dq : dq;
                if (ad > 3) continue;
                #pragma unroll
                for (int j = 0; j < 4; ++j) {
                    float a = acc[k][j];
                    if (dq == 0) {
                        a += M0[j];
                        a = fmaf(U.wy1b, M1[j], a);
                        a = fmaf(U.wy2c, M2[j], a);
                        a = fmaf(U.wy3d, M3[j], a);
                    } else if (ad == 1) {
                        a = fmaf(U.wy1a, M1[j], a);
                        a = fmaf(U.wy2b, M2[j], a);
                        a = fmaf(U.wy3c, M3[j], a);
                    } else if (ad == 2) {
                        a = fmaf(U.wy2a, M2[j], a);
                        a = fmaf(U.wy3b, M3[j], a);
                    } else {
                        a = fmaf(U.wy3a, M3[j], a);
                    }
                    acc[k][j] = a;
                }
            }
        }
        #pragma unroll
        for (int k = 0; k < 4; ++k) {
            const int Yo = yb0 + 2 * k;
            const float4 uv = ld4(p + (size_t)Yo * W + gx0);
            float4 o;
            o.x = fmaf(U.am, acc[k][0], uv.x);
            o.y = fmaf(U.am, acc[k][1], uv.y);
            o.z = fmaf(U.am, acc[k][2], uv.z);
            o.w = fmaf(U.am, acc[k][3], uv.w);
            *reinterpret_cast<float4*>(q + (size_t)Yo * W + gx0) = o;
        }
    } else {
        // ---------------- boundary band (y via table) ----------------
        const int ly = (band == 0) ? 0 : 1;
        for (int ri = 0; ri < 14; ++ri) {
            const int r = ly == 0 ? ri : (H - 14) + ri;
            float rb[20];
            #pragma unroll
            for (int m = 0; m < 5; ++m)
                *reinterpret_cast<float4*>(&rb[4 * m]) = ld4(p + (size_t)r * W + colm[m]);
            float M0[4], M1[4], M2[4], M3[4];
            rowM(U, rb, c, M0, M1, M2, M3);
            #pragma unroll
            for (int k = 0; k < 4; ++k) {
                const float* wr = &WYT.w[ly][g][ri][k][0];
                const float w0 = wr[0];
                const float w1 = wr[1] * U.sy1;
                const float w2 = wr[2] * U.sy2;
                const float w3 = wr[3] * U.sy3;
                #pragma unroll
                for (int j = 0; j < 4; ++j) {
                    float a = acc[k][j];
                    a = fmaf(w0, M0[j], a);
                    a = fmaf(w1, M1[j], a);
                    a = fmaf(w2, M2[j], a);
                    a = fmaf(w3, M3[j], a);
                    acc[k][j] = a;
                }
            }
        }
        #pragma unroll
        for (int k = 0; k < 4; ++k) {
            const int Yo = (ly == 0 ? 0 : H - 8) + g + 2 * k;
            const float4 uv = ld4(p + (size_t)Yo * W + gx0);
            float4 o;
            o.x = fmaf(U.am, acc[k][0], uv.x);
            o.y = fmaf(U.am, acc[k][1], uv.y);
            o.z = fmaf(U.am, acc[k][2], uv.z);
            o.w = fmaf(U.am, acc[k][3], uv.w);
            *reinterpret_cast<float4*>(q + (size_t)Yo * W + gx0) = o;
        }
    }
}

extern "C" void kernel_launch(void* const* d_in, const int* in_sizes, int n_in,
                              void* d_out, int out_size, void* d_ws, size_t ws_size,
                              hipStream_t stream) {
    const float* u     = (const float*)d_in[0];
    const float* alpha = (const float*)d_in[1];
    const float* beta  = (const float*)d_in[2];
    const float* ax    = (const float*)d_in[3];
    const float* ay    = (const float*)d_in[4];
    const float* es    = (const float*)d_in[5];
    float* out = (float*)d_out;

    int nimg = in_sizes[0] / IMG;            // 64 images
    dim3 block(256);
    dim3 grid((unsigned)(nimg * 64));        // 64 bands (8 rows) per image
    fused_band<<<grid, block, 0, stream>>>(u, out, alpha, beta, ax, ay, es);
}